// Round 2
// 323.102 us; speedup vs baseline: 1.0429x; 1.0429x over previous
//
#include <hip/hip_runtime.h>

// StainNormalization v2.1: LDS-transposed staging for perfect per-instruction coalescing.
// (v2 failed to compile: __builtin_nontemporal_* rejects HIP_vector_type<float,4>*.
//  Fix: use clang native ext_vector float4 for all 16B traffic.)
//
// out[d] = min(exp2(sum_c log2(x_c+1e-6) * (M[c][d]*gamma[d]) - beta[d]/ln2), 1)
// (exp2 >= 0 always, so the lower clamp is free)
//
// v1 problem: each thread owned 3 consecutive float4s (4 pixels, 48 B/lane span),
// so every global_load_dwordx4 had a 48 B inter-lane stride -> 24 cache lines per
// instruction at 1/3 utilization on BOTH load and store side (~4.2 TB/s effective).
//
// v2: per-instruction lane-contiguous global access (lane i <-> float4 i), with an
// LDS bounce to regroup float4-chunks into whole-pixel groups per thread:
//   Phase A: load  slot k = tid + i*256 (contiguous)  -> lds[swz(k)]
//   Phase B: read  slots 3t..3t+2 (one thread = 4 pixels), compute
//   Phase C: write results back to slots 3t..3t+2 (same thread -> no barrier vs B)
//   Phase D: read  slot k = tid + i*256 -> contiguous global store
// Swizzle swz(k) = k + (k>>3) (one pad slot per 8): both the linear-side (k
// consecutive) and pixel-side (k = 3t+j) b128 accesses land exactly 8 lanes on
// each of the 8 bank-groups -> conflict-free-equivalent ds_read/write_b128.
// LDS = 864 * 16 B = 13.8 KiB -> occupancy stays waves-limited (8 blocks/CU).

typedef float f4 __attribute__((ext_vector_type(4)));

constexpr int BLOCK = 256;
constexpr int SLOTS = 768;                  // float4 slots per block = BLOCK * 3
constexpr int LDS_SLOTS = SLOTS + SLOTS/8;  // 864 with pad slots
constexpr int PIXB = 1024;                  // pixels per block (= SLOTS*4/3)

__device__ __forceinline__ int swz(int k) { return k + (k >> 3); }

__global__ __launch_bounds__(BLOCK) void stain_norm_kernel(
    const float* __restrict__ x,
    const float* __restrict__ Mp,     // 3x3 row-major M[c*3+d]
    const float* __restrict__ gp,     // gamma[3]
    const float* __restrict__ bp,     // beta[3]
    float* __restrict__ out,
    int npix, int nfull)
{
    __shared__ f4 lds[LDS_SLOTS];

    // Uniform parameter loads (broadcast, cached)
    const float g0 = gp[0], g1 = gp[1], g2 = gp[2];
    const float A00 = Mp[0] * g0, A01 = Mp[1] * g1, A02 = Mp[2] * g2;
    const float A10 = Mp[3] * g0, A11 = Mp[4] * g1, A12 = Mp[5] * g2;
    const float A20 = Mp[6] * g0, A21 = Mp[7] * g1, A22 = Mp[8] * g2;
    const float INV_LN2 = 1.4426950408889634f;
    const float c0 = -bp[0] * INV_LN2;
    const float c1 = -bp[1] * INV_LN2;
    const float c2 = -bp[2] * INV_LN2;
    const float EPS = 1e-6f;

    const int t = threadIdx.x;
    const int b = blockIdx.x;

    if (b < nfull) {
        // ---- Phase A: contiguous global load -> swizzled LDS ----
        const f4* __restrict__ xv =
            reinterpret_cast<const f4*>(x) + (size_t)b * SLOTS;
#pragma unroll
        for (int i = 0; i < 3; ++i) {
            const int k = t + i * BLOCK;                 // lane-contiguous per instr
            lds[swz(k)] = __builtin_nontemporal_load(xv + k);
        }
        __syncthreads();

        // ---- Phase B: gather 4 whole pixels (12 floats) from LDS, compute ----
        float f[12];
#pragma unroll
        for (int j = 0; j < 3; ++j) {
            f4 v = lds[swz(3 * t + j)];
            f[4 * j + 0] = v.x; f[4 * j + 1] = v.y;
            f[4 * j + 2] = v.z; f[4 * j + 3] = v.w;
        }

        float o[12];
#pragma unroll
        for (int j = 0; j < 4; ++j) {
            const float l0 = __builtin_amdgcn_logf(f[3 * j + 0] + EPS);
            const float l1 = __builtin_amdgcn_logf(f[3 * j + 1] + EPS);
            const float l2 = __builtin_amdgcn_logf(f[3 * j + 2] + EPS);
            o[3 * j + 0] = fminf(__builtin_amdgcn_exp2f(fmaf(l0, A00, fmaf(l1, A10, fmaf(l2, A20, c0)))), 1.0f);
            o[3 * j + 1] = fminf(__builtin_amdgcn_exp2f(fmaf(l0, A01, fmaf(l1, A11, fmaf(l2, A21, c1)))), 1.0f);
            o[3 * j + 2] = fminf(__builtin_amdgcn_exp2f(fmaf(l0, A02, fmaf(l1, A12, fmaf(l2, A22, c2)))), 1.0f);
        }

        // ---- Phase C: results back to the same slots (same owner -> no barrier) ----
#pragma unroll
        for (int j = 0; j < 3; ++j) {
            f4 v;
            v.x = o[4 * j + 0]; v.y = o[4 * j + 1];
            v.z = o[4 * j + 2]; v.w = o[4 * j + 3];
            lds[swz(3 * t + j)] = v;
        }
        __syncthreads();

        // ---- Phase D: swizzled LDS -> contiguous global store ----
        f4* __restrict__ ov =
            reinterpret_cast<f4*>(out) + (size_t)b * SLOTS;
#pragma unroll
        for (int i = 0; i < 3; ++i) {
            const int k = t + i * BLOCK;                 // lane-contiguous per instr
            __builtin_nontemporal_store(lds[swz(k)], ov + k);
        }
    } else {
        // ---- Tail block: scalar per-pixel (bench shape divides evenly; this is
        // correctness insurance only) ----
        for (int q = nfull * PIXB + t; q < npix; q += BLOCK) {
            const float l0 = __builtin_amdgcn_logf(x[3 * q + 0] + EPS);
            const float l1 = __builtin_amdgcn_logf(x[3 * q + 1] + EPS);
            const float l2 = __builtin_amdgcn_logf(x[3 * q + 2] + EPS);
            out[3 * q + 0] = fminf(__builtin_amdgcn_exp2f(fmaf(l0, A00, fmaf(l1, A10, fmaf(l2, A20, c0)))), 1.0f);
            out[3 * q + 1] = fminf(__builtin_amdgcn_exp2f(fmaf(l0, A01, fmaf(l1, A11, fmaf(l2, A21, c1)))), 1.0f);
            out[3 * q + 2] = fminf(__builtin_amdgcn_exp2f(fmaf(l0, A02, fmaf(l1, A12, fmaf(l2, A22, c2)))), 1.0f);
        }
    }
}

extern "C" void kernel_launch(void* const* d_in, const int* in_sizes, int n_in,
                              void* d_out, int out_size, void* d_ws, size_t ws_size,
                              hipStream_t stream) {
    const float* x     = (const float*)d_in[0];
    const float* M     = (const float*)d_in[1];
    const float* gamma = (const float*)d_in[2];
    const float* beta  = (const float*)d_in[3];
    float* out = (float*)d_out;

    const int n = in_sizes[0];        // total floats (B*H*W*3)
    const int npix = n / 3;           // pixels
    const int nfull = npix / PIXB;    // blocks with 1024 whole pixels
    const int grid = nfull + ((npix % PIXB) ? 1 : 0);

    stain_norm_kernel<<<grid, BLOCK, 0, stream>>>(x, M, gamma, beta, out, npix, nfull);
}

// Round 3
// 321.953 us; speedup vs baseline: 1.0466x; 1.0036x over previous
//
#include <hip/hip_runtime.h>

// StainNormalization v3: barrier-free wave-private LDS staging.
//
// out[d] = min(exp2(sum_c log2(x_c+1e-6) * (M[c][d]*gamma[d]) - beta[d]/ln2), 1)
// (exp2 >= 0 always, so the lower clamp is free)
//
// v2.1 (LDS-transposed staging, block-wide) reached ~81us inferred (~5 TB/s).
// Remaining overhead theory: the two __syncthreads() per block couple 4 waves
// to the slowest HBM return. The regroup is wave-local by construction
// (each wave's 256 pixels = 192 float4s), so give each wave a PRIVATE LDS
// window and drop both barriers: per-wave lgkmcnt ordering (compiler-inserted)
// is sufficient for ds_write -> ds_read correctness within one wave.
//
// Swizzle swz(k) = k + (k>>3) (pad slot per 8): linear-side (k = lane+64i) and
// pixel-side (k = 3*lane+j) b128 accesses each land exactly 8 lanes per
// bank-group -> conflict-free-equivalent. Wave window stride 216 slots
// (216 % 8 == 0) preserves the bank-group structure.
// LDS = 4 waves * 216 * 16 B = 13.8 KiB -> 8 blocks/CU (waves-limited).

typedef float f4 __attribute__((ext_vector_type(4)));

constexpr int BLOCK = 256;
constexpr int WAVES = 4;
constexpr int WSLOTS = 192;                    // float4 slots per wave (64 lanes * 3)
constexpr int WPAD = WSLOTS + WSLOTS / 8;      // 216 with pad slots
constexpr int LDS_SLOTS = WAVES * WPAD;        // 864
constexpr int SLOTS = BLOCK * 3;               // 768 float4 slots per block
constexpr int PIXB = 1024;                     // pixels per block

__device__ __forceinline__ int swz(int k) { return k + (k >> 3); }

__global__ __launch_bounds__(BLOCK) void stain_norm_kernel(
    const float* __restrict__ x,
    const float* __restrict__ Mp,     // 3x3 row-major M[c*3+d]
    const float* __restrict__ gp,     // gamma[3]
    const float* __restrict__ bp,     // beta[3]
    float* __restrict__ out,
    int npix, int nfull)
{
    __shared__ f4 lds[LDS_SLOTS];

    // Uniform parameter loads (broadcast, cached)
    const float g0 = gp[0], g1 = gp[1], g2 = gp[2];
    const float A00 = Mp[0] * g0, A01 = Mp[1] * g1, A02 = Mp[2] * g2;
    const float A10 = Mp[3] * g0, A11 = Mp[4] * g1, A12 = Mp[5] * g2;
    const float A20 = Mp[6] * g0, A21 = Mp[7] * g1, A22 = Mp[8] * g2;
    const float INV_LN2 = 1.4426950408889634f;
    const float c0 = -bp[0] * INV_LN2;
    const float c1 = -bp[1] * INV_LN2;
    const float c2 = -bp[2] * INV_LN2;
    const float EPS = 1e-6f;

    const int t    = threadIdx.x;
    const int b    = blockIdx.x;
    const int wid  = t >> 6;
    const int lane = t & 63;

    if (b < nfull) {
        f4* __restrict__ wlds = lds + wid * WPAD;   // wave-private window

        // ---- Phase A: contiguous global load -> swizzled wave-private LDS ----
        const f4* __restrict__ xv =
            reinterpret_cast<const f4*>(x) + (size_t)b * SLOTS + wid * WSLOTS;
#pragma unroll
        for (int i = 0; i < 3; ++i) {
            const int k = lane + i * 64;             // lane-contiguous per instr
            wlds[swz(k)] = __builtin_nontemporal_load(xv + k);
        }
        // no barrier: same-wave ds_write -> ds_read ordered by lgkmcnt

        // ---- Phase B: gather 4 whole pixels (12 floats) from LDS, compute ----
        float f[12];
#pragma unroll
        for (int j = 0; j < 3; ++j) {
            f4 v = wlds[swz(3 * lane + j)];
            f[4 * j + 0] = v.x; f[4 * j + 1] = v.y;
            f[4 * j + 2] = v.z; f[4 * j + 3] = v.w;
        }

        float o[12];
#pragma unroll
        for (int j = 0; j < 4; ++j) {
            const float l0 = __builtin_amdgcn_logf(f[3 * j + 0] + EPS);
            const float l1 = __builtin_amdgcn_logf(f[3 * j + 1] + EPS);
            const float l2 = __builtin_amdgcn_logf(f[3 * j + 2] + EPS);
            o[3 * j + 0] = fminf(__builtin_amdgcn_exp2f(fmaf(l0, A00, fmaf(l1, A10, fmaf(l2, A20, c0)))), 1.0f);
            o[3 * j + 1] = fminf(__builtin_amdgcn_exp2f(fmaf(l0, A01, fmaf(l1, A11, fmaf(l2, A21, c1)))), 1.0f);
            o[3 * j + 2] = fminf(__builtin_amdgcn_exp2f(fmaf(l0, A02, fmaf(l1, A12, fmaf(l2, A22, c2)))), 1.0f);
        }

        // ---- Phase C: results back to the same slots (same wave, lgkmcnt-ordered) ----
#pragma unroll
        for (int j = 0; j < 3; ++j) {
            f4 v;
            v.x = o[4 * j + 0]; v.y = o[4 * j + 1];
            v.z = o[4 * j + 2]; v.w = o[4 * j + 3];
            wlds[swz(3 * lane + j)] = v;
        }

        // ---- Phase D: swizzled LDS -> contiguous global store ----
        f4* __restrict__ ov =
            reinterpret_cast<f4*>(out) + (size_t)b * SLOTS + wid * WSLOTS;
#pragma unroll
        for (int i = 0; i < 3; ++i) {
            const int k = lane + i * 64;             // lane-contiguous per instr
            __builtin_nontemporal_store(wlds[swz(k)], ov + k);
        }
    } else {
        // ---- Tail block: scalar per-pixel (bench shape divides evenly; this is
        // correctness insurance only) ----
        for (int q = nfull * PIXB + t; q < npix; q += BLOCK) {
            const float l0 = __builtin_amdgcn_logf(x[3 * q + 0] + EPS);
            const float l1 = __builtin_amdgcn_logf(x[3 * q + 1] + EPS);
            const float l2 = __builtin_amdgcn_logf(x[3 * q + 2] + EPS);
            out[3 * q + 0] = fminf(__builtin_amdgcn_exp2f(fmaf(l0, A00, fmaf(l1, A10, fmaf(l2, A20, c0)))), 1.0f);
            out[3 * q + 1] = fminf(__builtin_amdgcn_exp2f(fmaf(l0, A01, fmaf(l1, A11, fmaf(l2, A21, c1)))), 1.0f);
            out[3 * q + 2] = fminf(__builtin_amdgcn_exp2f(fmaf(l0, A02, fmaf(l1, A12, fmaf(l2, A22, c2)))), 1.0f);
        }
    }
}

extern "C" void kernel_launch(void* const* d_in, const int* in_sizes, int n_in,
                              void* d_out, int out_size, void* d_ws, size_t ws_size,
                              hipStream_t stream) {
    const float* x     = (const float*)d_in[0];
    const float* M     = (const float*)d_in[1];
    const float* gamma = (const float*)d_in[2];
    const float* beta  = (const float*)d_in[3];
    float* out = (float*)d_out;

    const int n = in_sizes[0];        // total floats (B*H*W*3)
    const int npix = n / 3;           // pixels
    const int nfull = npix / PIXB;    // blocks with 1024 whole pixels
    const int grid = nfull + ((npix % PIXB) ? 1 : 0);

    stain_norm_kernel<<<grid, BLOCK, 0, stream>>>(x, M, gamma, beta, out, npix, nfull);
}